// Round 2
// baseline (619.989 us; speedup 1.0000x reference)
//
#include <hip/hip_runtime.h>
#include <stdint.h>

#define Bb 8
#define Cc 256
#define Nn 2304
#define QTILES 36   // Nn / 64
#define KTILES 72   // Nn / 32

typedef unsigned short u16;
typedef __bf16 bf16;
typedef bf16 bf16x8 __attribute__((ext_vector_type(8)));
typedef u16  u16x8  __attribute__((ext_vector_type(8)));
typedef float f32x4 __attribute__((ext_vector_type(4)));

static __device__ __forceinline__ u16 f2bf(float f) {
  unsigned u = __builtin_bit_cast(unsigned, f);
  return (u16)((u + 0x7fffu + ((u >> 16) & 1u)) >> 16);
}
static __device__ __forceinline__ float bf2f(u16 h) {
  unsigned u = ((unsigned)h) << 16;
  return __builtin_bit_cast(float, u);
}
static __device__ __forceinline__ bf16x8 asbf(u16x8 v) {
  return __builtin_bit_cast(bf16x8, v);
}

// ---------------------------------------------------------------------------
// Prep: convert Wq,Wk,Wv (fp32 [C][C]) to hi/lo bf16 pairs. grid 96 x 256.
// WHi/WLo layout: [3][C*C] u16.
// ---------------------------------------------------------------------------
__global__ void prep_kernel(const float* __restrict__ Wq,
                            const float* __restrict__ Wk,
                            const float* __restrict__ Wv,
                            u16* __restrict__ WHi, u16* __restrict__ WLo)
{
  const int tid = blockIdx.x * 256 + threadIdx.x;   // 0..24575
  const int m   = tid >> 13;                        // 0..2
  const int off = (tid & 8191) * 8;
  const float* src = (m == 0) ? Wq : (m == 1) ? Wk : Wv;
  const f32x4 a = *(const f32x4*)(src + off);
  const f32x4 c = *(const f32x4*)(src + off + 4);
  u16x8 hi, lo;
#pragma unroll
  for (int j = 0; j < 4; ++j) {
    u16 h = f2bf(a[j]); hi[j] = h; lo[j] = f2bf(a[j] - bf2f(h));
    u16 h2 = f2bf(c[j]); hi[j + 4] = h2; lo[j + 4] = f2bf(c[j] - bf2f(h2));
  }
  *(u16x8*)(WHi + (size_t)m * 65536 + off) = hi;
  *(u16x8*)(WLo + (size_t)m * 65536 + off) = lo;
}

// ---------------------------------------------------------------------------
// Projection: Q,K as hi/lo bf16 [B][N][C] pairs (3-term hi/lo MFMA, ~fp32
// accurate), V^T as bf16 [B][C][N] (1-term). x/y staged in LDS as fp32
// [64 tok][256 c], 16B-chunk double-XOR swizzle. grid (36,8), block 256.
// ---------------------------------------------------------------------------
__global__ __launch_bounds__(256, 2) void proj_kernel(
    const float* __restrict__ x, const float* __restrict__ y,
    const u16* __restrict__ WHi, const u16* __restrict__ WLo,
    const float* __restrict__ bq, const float* __restrict__ bk,
    const float* __restrict__ bv,
    u16* __restrict__ QHi, u16* __restrict__ QLo,
    u16* __restrict__ KHi, u16* __restrict__ KLo,
    u16* __restrict__ Vw)
{
  __shared__ float sT[64 * 256];   // 64 KB
  const int t    = threadIdx.x;
  const int b    = blockIdx.y;
  const int q0   = blockIdx.x * 64;
  const int lane = t & 63;
  const int w    = t >> 6;
  const int quad = lane >> 4;
  const int l15  = lane & 15;

  const int tq = t & 15;   // token group of 4
  const int c0 = t >> 4;   // channel low part

  // ---- stage x: fp32 [C][N] -> LDS [tok][c] swizzled ----
  for (int it = 0; it < 16; ++it) {
    const int c = c0 + it * 16;
    const f32x4 xv = *(const f32x4*)(x + ((size_t)b * Cc + c) * Nn + q0 + tq * 4);
#pragma unroll
    for (int j = 0; j < 4; ++j) {
      const int n = tq * 4 + j;
      const int g = (n & 7) ^ ((n >> 3) & 7);
      sT[n * 256 + (((c >> 2) ^ g) << 2) + (c & 3)] = xv[j];
    }
  }
  __syncthreads();

  // ---- preload x hi/lo A-fragments ----
  u16x8 xhi[8], xlo[8];
  {
    const int trow = w * 16 + l15;
    const int g = (trow & 7) ^ ((trow >> 3) & 7);
#pragma unroll
    for (int kc = 0; kc < 8; ++kc) {
      const int ch0 = (kc * 8 + quad * 2) ^ g;
      const int ch1 = (kc * 8 + quad * 2 + 1) ^ g;
      const f32x4 a = *(const f32x4*)(sT + trow * 256 + ch0 * 4);
      const f32x4 c = *(const f32x4*)(sT + trow * 256 + ch1 * 4);
      u16x8 hi, lo;
#pragma unroll
      for (int j = 0; j < 4; ++j) {
        u16 h = f2bf(a[j]); hi[j] = h; lo[j] = f2bf(a[j] - bf2f(h));
        u16 h2 = f2bf(c[j]); hi[j + 4] = h2; lo[j + 4] = f2bf(c[j] - bf2f(h2));
      }
      xhi[kc] = hi; xlo[kc] = lo;
    }
  }
  __syncthreads();   // all waves done reading x before y overwrites

  // ---- stage y (overlaps Q compute below) ----
  for (int it = 0; it < 16; ++it) {
    const int c = c0 + it * 16;
    const f32x4 yv = *(const f32x4*)(y + ((size_t)b * Cc + c) * Nn + q0 + tq * 4);
#pragma unroll
    for (int j = 0; j < 4; ++j) {
      const int n = tq * 4 + j;
      const int g = (n & 7) ^ ((n >> 3) & 7);
      sT[n * 256 + (((c >> 2) ^ g) << 2) + (c & 3)] = yv[j];
    }
  }

  // ---- Q = x Wq^T + bq (3-term hi/lo) ----
#pragma unroll 1
  for (int cb = 0; cb < 16; ++cb) {
    f32x4 acc = {0.f, 0.f, 0.f, 0.f};
    const int co = cb * 16 + l15;
    const u16* whiR = WHi + (size_t)co * 256;
    const u16* wloR = WLo + (size_t)co * 256;
#pragma unroll
    for (int kc = 0; kc < 8; ++kc) {
      const u16x8 whi = *(const u16x8*)(whiR + kc * 32 + quad * 8);
      const u16x8 wlo = *(const u16x8*)(wloR + kc * 32 + quad * 8);
      acc = __builtin_amdgcn_mfma_f32_16x16x32_bf16(asbf(xhi[kc]), asbf(whi), acc, 0, 0, 0);
      acc = __builtin_amdgcn_mfma_f32_16x16x32_bf16(asbf(xhi[kc]), asbf(wlo), acc, 0, 0, 0);
      acc = __builtin_amdgcn_mfma_f32_16x16x32_bf16(asbf(xlo[kc]), asbf(whi), acc, 0, 0, 0);
    }
    const float bias = bq[co];
    const size_t base = ((size_t)b * Nn + q0 + w * 16 + quad * 4) * Cc + co;
#pragma unroll
    for (int r = 0; r < 4; ++r) {
      const float q = acc[r] + bias;
      const u16 h = f2bf(q);
      QHi[base + (size_t)r * Cc] = h;
      QLo[base + (size_t)r * Cc] = f2bf(q - bf2f(h));
    }
  }
  __syncthreads();   // y staged

  // ---- preload y hi/lo A-fragments ----
  u16x8 yhi[8], ylo[8];
  {
    const int trow = w * 16 + l15;
    const int g = (trow & 7) ^ ((trow >> 3) & 7);
#pragma unroll
    for (int kc = 0; kc < 8; ++kc) {
      const int ch0 = (kc * 8 + quad * 2) ^ g;
      const int ch1 = (kc * 8 + quad * 2 + 1) ^ g;
      const f32x4 a = *(const f32x4*)(sT + trow * 256 + ch0 * 4);
      const f32x4 c = *(const f32x4*)(sT + trow * 256 + ch1 * 4);
      u16x8 hi, lo;
#pragma unroll
      for (int j = 0; j < 4; ++j) {
        u16 h = f2bf(a[j]); hi[j] = h; lo[j] = f2bf(a[j] - bf2f(h));
        u16 h2 = f2bf(c[j]); hi[j + 4] = h2; lo[j + 4] = f2bf(c[j] - bf2f(h2));
      }
      yhi[kc] = hi; ylo[kc] = lo;
    }
  }

  // ---- K = y Wk^T + bk (3-term hi/lo) ----
#pragma unroll 1
  for (int cb = 0; cb < 16; ++cb) {
    f32x4 acc = {0.f, 0.f, 0.f, 0.f};
    const int co = cb * 16 + l15;
    const u16* whiR = WHi + 65536 + (size_t)co * 256;
    const u16* wloR = WLo + 65536 + (size_t)co * 256;
#pragma unroll
    for (int kc = 0; kc < 8; ++kc) {
      const u16x8 whi = *(const u16x8*)(whiR + kc * 32 + quad * 8);
      const u16x8 wlo = *(const u16x8*)(wloR + kc * 32 + quad * 8);
      acc = __builtin_amdgcn_mfma_f32_16x16x32_bf16(asbf(yhi[kc]), asbf(whi), acc, 0, 0, 0);
      acc = __builtin_amdgcn_mfma_f32_16x16x32_bf16(asbf(yhi[kc]), asbf(wlo), acc, 0, 0, 0);
      acc = __builtin_amdgcn_mfma_f32_16x16x32_bf16(asbf(ylo[kc]), asbf(whi), acc, 0, 0, 0);
    }
    const float bias = bk[co];
    const size_t base = ((size_t)b * Nn + q0 + w * 16 + quad * 4) * Cc + co;
#pragma unroll
    for (int r = 0; r < 4; ++r) {
      const float k = acc[r] + bias;
      const u16 h = f2bf(k);
      KHi[base + (size_t)r * Cc] = h;
      KLo[base + (size_t)r * Cc] = f2bf(k - bf2f(h));
    }
  }

  // ---- V^T = Wv y^T + bv (1-term, c_out is M dim) ----
#pragma unroll 1
  for (int mt = 0; mt < 4; ++mt) {
    const int co = w * 64 + mt * 16 + l15;
    u16x8 wf[8];
#pragma unroll
    for (int kc = 0; kc < 8; ++kc)
      wf[kc] = *(const u16x8*)(WHi + 131072 + (size_t)co * 256 + kc * 32 + quad * 8);
    const int corow = w * 64 + mt * 16 + quad * 4;
    float bias[4];
#pragma unroll
    for (int r = 0; r < 4; ++r) bias[r] = bv[corow + r];
#pragma unroll 1
    for (int nt = 0; nt < 4; ++nt) {
      f32x4 acc = {0.f, 0.f, 0.f, 0.f};
      const int tr = nt * 16 + l15;
      const int g = (tr & 7) ^ ((tr >> 3) & 7);
#pragma unroll
      for (int kc = 0; kc < 8; ++kc) {
        const int ch0 = (kc * 8 + quad * 2) ^ g;
        const int ch1 = (kc * 8 + quad * 2 + 1) ^ g;
        const f32x4 a = *(const f32x4*)(sT + tr * 256 + ch0 * 4);
        const f32x4 c = *(const f32x4*)(sT + tr * 256 + ch1 * 4);
        const u16x8 yfr = {f2bf(a[0]), f2bf(a[1]), f2bf(a[2]), f2bf(a[3]),
                           f2bf(c[0]), f2bf(c[1]), f2bf(c[2]), f2bf(c[3])};
        acc = __builtin_amdgcn_mfma_f32_16x16x32_bf16(asbf(wf[kc]), asbf(yfr), acc, 0, 0, 0);
      }
      u16* vout = Vw + ((size_t)b * Cc + corow) * Nn + q0 + nt * 16 + l15;
#pragma unroll
      for (int r = 0; r < 4; ++r)
        vout[(size_t)r * Nn] = f2bf(acc[r] + bias[r]);
    }
  }
}

// ---------------------------------------------------------------------------
// Flash attention. grid (36,8), block 256 (4 waves x 16 queries), 32-key
// tiles. QK^T is 3-term hi/lo (fp32-accurate logits); PV is bf16.
// LDS 52 KB: sKhi/sKlo [32][256], sV [256][32], sP per-wave 16x32.
// ---------------------------------------------------------------------------
__global__ __launch_bounds__(256, 2) void attn_kernel(
    const u16* __restrict__ QHi, const u16* __restrict__ QLo,
    const u16* __restrict__ KHi, const u16* __restrict__ KLo,
    const u16* __restrict__ Vw, float* __restrict__ out)
{
  __shared__ u16 sKhi[32 * 256];
  __shared__ u16 sKlo[32 * 256];
  __shared__ u16 sV[256 * 32];
  __shared__ u16 sP[4 * 512];
  const int t    = threadIdx.x;
  const int b    = blockIdx.y;
  const int q0   = blockIdx.x * 64;
  const int lane = t & 63;
  const int w    = t >> 6;
  const int quad = lane >> 4;
  const int l15  = lane & 15;
  const float L2E = 1.44269504088896f;

  u16x8 qhi[8], qlo[8];
  {
    const size_t qrow = ((size_t)b * Nn + q0 + w * 16 + l15) * Cc;
#pragma unroll
    for (int kc = 0; kc < 8; ++kc) {
      qhi[kc] = *(const u16x8*)(QHi + qrow + kc * 32 + quad * 8);
      qlo[kc] = *(const u16x8*)(QLo + qrow + kc * 32 + quad * 8);
    }
  }

  f32x4 o[16];
#pragma unroll
  for (int i = 0; i < 16; ++i) o[i] = (f32x4){0.f, 0.f, 0.f, 0.f};
  float mrow[4] = {-3e38f, -3e38f, -3e38f, -3e38f};
  float lrow[4] = {0.f, 0.f, 0.f, 0.f};

  const u16* KhiB = KHi + (size_t)b * Nn * Cc;
  const u16* KloB = KLo + (size_t)b * Nn * Cc;
  const u16* VB   = Vw + (size_t)b * Cc * Nn;
  const int gl = (l15 & 3) ^ ((l15 >> 2) & 3);   // double-XOR hash

  for (int kb = 0; kb < KTILES; ++kb) {
    __syncthreads();
    // ---- stage K hi/lo [32][256] (chunk swizzle ^ (row&7)) ----
#pragma unroll
    for (int it = 0; it < 4; ++it) {
      const int cid = it * 256 + t;
      const int row = cid >> 5;
      const int i   = cid & 31;
      const int k   = i ^ (row & 7);
      const size_t gsrc = (size_t)(kb * 32 + row) * Cc + k * 8;
      *(u16x8*)(sKhi + row * 256 + i * 8) = *(const u16x8*)(KhiB + gsrc);
      *(u16x8*)(sKlo + row * 256 + i * 8) = *(const u16x8*)(KloB + gsrc);
    }
    // ---- stage V^T [256][32] (double-XOR swizzle) ----
#pragma unroll
    for (int it = 0; it < 4; ++it) {
      const int cid = it * 256 + t;
      const int row = cid >> 2;
      const int i   = cid & 3;
      const int gv  = (row & 3) ^ ((row >> 2) & 3);
      const int k   = i ^ gv;
      *(u16x8*)(sV + row * 32 + i * 8) =
          *(const u16x8*)(VB + (size_t)row * Nn + kb * 32 + k * 8);
    }
    __syncthreads();

    // ---- S = Q K^T, 3-term hi/lo, two 16-key blocks interleaved ----
    f32x4 s0 = {0.f, 0.f, 0.f, 0.f}, s1 = {0.f, 0.f, 0.f, 0.f};
#pragma unroll
    for (int kc = 0; kc < 8; ++kc) {
      const int ch = ((kc * 4 + quad) ^ (l15 & 7)) * 8;
      const u16x8 kh0 = *(const u16x8*)(sKhi + l15 * 256 + ch);
      const u16x8 kl0 = *(const u16x8*)(sKlo + l15 * 256 + ch);
      const u16x8 kh1 = *(const u16x8*)(sKhi + (16 + l15) * 256 + ch);
      const u16x8 kl1 = *(const u16x8*)(sKlo + (16 + l15) * 256 + ch);
      s0 = __builtin_amdgcn_mfma_f32_16x16x32_bf16(asbf(qhi[kc]), asbf(kh0), s0, 0, 0, 0);
      s1 = __builtin_amdgcn_mfma_f32_16x16x32_bf16(asbf(qhi[kc]), asbf(kh1), s1, 0, 0, 0);
      s0 = __builtin_amdgcn_mfma_f32_16x16x32_bf16(asbf(qhi[kc]), asbf(kl0), s0, 0, 0, 0);
      s1 = __builtin_amdgcn_mfma_f32_16x16x32_bf16(asbf(qhi[kc]), asbf(kl1), s1, 0, 0, 0);
      s0 = __builtin_amdgcn_mfma_f32_16x16x32_bf16(asbf(qlo[kc]), asbf(kh0), s0, 0, 0, 0);
      s1 = __builtin_amdgcn_mfma_f32_16x16x32_bf16(asbf(qlo[kc]), asbf(kh1), s1, 0, 0, 0);
    }

    // ---- online softmax over this 32-key tile ----
    float al[4];
#pragma unroll
    for (int r = 0; r < 4; ++r) {
      float m0 = fmaxf(s0[r], s1[r]);
#pragma unroll
      for (int off = 1; off < 16; off <<= 1)
        m0 = fmaxf(m0, __shfl_xor(m0, off, 64));
      const float mn = fmaxf(mrow[r], m0);
      al[r] = exp2f((mrow[r] - mn) * L2E);
      mrow[r] = mn;
      const float p0 = exp2f((s0[r] - mn) * L2E);
      const float p1 = exp2f((s1[r] - mn) * L2E);
      s0[r] = p0; s1[r] = p1;
      float sum = p0 + p1;
#pragma unroll
      for (int off = 1; off < 16; off <<= 1)
        sum += __shfl_xor(sum, off, 64);
      lrow[r] = lrow[r] * al[r] + sum;
    }
#pragma unroll
    for (int i = 0; i < 16; ++i) {
#pragma unroll
      for (int r = 0; r < 4; ++r) o[i][r] *= al[r];
    }

    // ---- P: C/D layout -> LDS (wave-local) -> A layout ----
    {
      u16* P = sP + w * 512;
      const int kch0 = l15 >> 3;        // key chunk of key=l15
#pragma unroll
      for (int r = 0; r < 4; ++r) {
        const int row = quad * 4 + r;   // g(row) = r ^ quad
        const int gx = r ^ quad;
        P[row * 32 + ((kch0 ^ gx) << 3) + (l15 & 7)] = f2bf(s0[r]);
        P[row * 32 + (((2 + kch0) ^ gx) << 3) + (l15 & 7)] = f2bf(s1[r]);
      }
    }
    __builtin_amdgcn_s_waitcnt(0xC07F);  // lgkmcnt(0): P writes visible
    u16x8 pf = *(const u16x8*)(sP + w * 512 + l15 * 32 + ((quad ^ gl) << 3));

    // ---- O += P V (16 independent chains, K=32 in one MFMA) ----
#pragma unroll
    for (int cb2 = 0; cb2 < 16; ++cb2) {
      const int c = cb2 * 16 + l15;     // g(c) == gl
      const u16x8 vf = *(const u16x8*)(sV + c * 32 + ((quad ^ gl) << 3));
      o[cb2] = __builtin_amdgcn_mfma_f32_16x16x32_bf16(asbf(pf), asbf(vf), o[cb2], 0, 0, 0);
    }
  }

  // ---- epilogue: out[b][c][n] = o / l ----
#pragma unroll
  for (int cb2 = 0; cb2 < 16; ++cb2) {
    const int c = cb2 * 16 + l15;
    float* op = out + ((size_t)b * Cc + c) * Nn + q0 + w * 16 + quad * 4;
    f32x4 v;
#pragma unroll
    for (int r = 0; r < 4; ++r) v[r] = o[cb2][r] / lrow[r];
    *(f32x4*)op = v;
  }
}

extern "C" void kernel_launch(void* const* d_in, const int* in_sizes, int n_in,
                              void* d_out, int out_size, void* d_ws, size_t ws_size,
                              hipStream_t stream) {
  const float* x  = (const float*)d_in[0];
  const float* y  = (const float*)d_in[1];
  const float* Wq = (const float*)d_in[2];
  const float* bq = (const float*)d_in[3];
  const float* Wk = (const float*)d_in[4];
  const float* bk = (const float*)d_in[5];
  const float* Wv = (const float*)d_in[6];
  const float* bv = (const float*)d_in[7];
  float* out = (float*)d_out;

  const size_t NC = (size_t)Bb * Nn * Cc;   // 4,718,592
  u16* QHi = (u16*)d_ws;
  u16* QLo = QHi + NC;
  u16* KHi = QLo + NC;
  u16* KLo = KHi + NC;
  u16* Vw  = KLo + NC;
  u16* WHi = Vw + NC;
  u16* WLo = WHi + 3 * 65536;

  hipLaunchKernelGGL(prep_kernel, dim3(96), dim3(256), 0, stream,
                     Wq, Wk, Wv, WHi, WLo);
  dim3 grid(QTILES, Bb), blk(256);
  hipLaunchKernelGGL(proj_kernel, grid, blk, 0, stream,
                     x, y, WHi, WLo, bq, bk, bv, QHi, QLo, KHi, KLo, Vw);
  hipLaunchKernelGGL(attn_kernel, grid, blk, 0, stream,
                     QHi, QLo, KHi, KLo, Vw, out);
}

// Round 3
// 431.571 us; speedup vs baseline: 1.4366x; 1.4366x over previous
//
#include <hip/hip_runtime.h>
#include <stdint.h>

#define Bb 8
#define Cc 256
#define Nn 2304
#define QTILES 36   // Nn / 64
#define KSPLIT 2
#define TPS 36      // 32-key tiles per split: 2304 / 32 / KSPLIT
#define L2E 1.44269504088896f

typedef unsigned short u16;
typedef __bf16 bf16;
typedef bf16 bf16x8 __attribute__((ext_vector_type(8)));
typedef u16  u16x8  __attribute__((ext_vector_type(8)));
typedef float f32x4 __attribute__((ext_vector_type(4)));

static __device__ __forceinline__ u16 f2bf(float f) {
  unsigned u = __builtin_bit_cast(unsigned, f);
  return (u16)((u + 0x7fffu + ((u >> 16) & 1u)) >> 16);
}
static __device__ __forceinline__ float bf2f(u16 h) {
  unsigned u = ((unsigned)h) << 16;
  return __builtin_bit_cast(float, u);
}
static __device__ __forceinline__ bf16x8 asbf(u16x8 v) {
  return __builtin_bit_cast(bf16x8, v);
}
static __device__ __forceinline__ f32x4 mfma16(u16x8 a, u16x8 b, f32x4 c) {
  return __builtin_amdgcn_mfma_f32_16x16x32_bf16(asbf(a), asbf(b), c, 0, 0, 0);
}

// ---------------------------------------------------------------------------
// Prep: Wq,Wk,Wv fp32 [C][C] -> hi/lo bf16. WHi/WLo: [3][C*C] u16.
// ---------------------------------------------------------------------------
__global__ void prep_kernel(const float* __restrict__ Wq,
                            const float* __restrict__ Wk,
                            const float* __restrict__ Wv,
                            u16* __restrict__ WHi, u16* __restrict__ WLo)
{
  const int tid = blockIdx.x * 256 + threadIdx.x;   // 0..24575
  const int m   = tid >> 13;
  const int off = (tid & 8191) * 8;
  const float* src = (m == 0) ? Wq : (m == 1) ? Wk : Wv;
  const f32x4 a = *(const f32x4*)(src + off);
  const f32x4 c = *(const f32x4*)(src + off + 4);
  u16x8 hi, lo;
#pragma unroll
  for (int j = 0; j < 4; ++j) {
    u16 h = f2bf(a[j]); hi[j] = h; lo[j] = f2bf(a[j] - bf2f(h));
    u16 h2 = f2bf(c[j]); hi[j + 4] = h2; lo[j + 4] = f2bf(c[j] - bf2f(h2));
  }
  *(u16x8*)(WHi + (size_t)m * 65536 + off) = hi;
  *(u16x8*)(WLo + (size_t)m * 65536 + off) = lo;
}

// ---------------------------------------------------------------------------
// Projection, split by output: z=0 Q (hi/lo), z=1 K (hi/lo), z=2 V^T (bf16).
// grid (8, 36, 3) — blockIdx.x = batch for XCD/L2 affinity. Block 256.
// LDS 32 KB: input tile staged as hi/lo bf16 [64 tok][256 c], 16B-chunk
// XOR swizzle (chunk ^ ((n&7)^(n>>3))).
// ---------------------------------------------------------------------------
__global__ __launch_bounds__(256, 3) void proj_kernel(
    const float* __restrict__ x, const float* __restrict__ y,
    const u16* __restrict__ WHi, const u16* __restrict__ WLo,
    const float* __restrict__ bq, const float* __restrict__ bk,
    const float* __restrict__ bv,
    u16* __restrict__ QHi, u16* __restrict__ QLo,
    u16* __restrict__ KHi, u16* __restrict__ KLo,
    u16* __restrict__ Vw)
{
  __shared__ u16 sHi[64 * 256];
  __shared__ u16 sLo[64 * 256];
  const int t    = threadIdx.x;
  const int b    = blockIdx.x;
  const int q0   = blockIdx.y * 64;
  const int z    = blockIdx.z;
  const int lane = t & 63;
  const int w    = t >> 6;
  const int quad = lane >> 4;
  const int l15  = lane & 15;

  // ---- stage input tile ----
  {
    const float* src = (z == 0) ? x : y;
    const int tq = t & 15;
    const int c0 = t >> 4;
    const bool wantlo = (z != 2);
    for (int it = 0; it < 16; ++it) {
      const int c = c0 + it * 16;
      const f32x4 v = *(const f32x4*)(src + ((size_t)b * Cc + c) * Nn + q0 + tq * 4);
#pragma unroll
      for (int j = 0; j < 4; ++j) {
        const int n = tq * 4 + j;
        const int g = (n & 7) ^ (n >> 3);
        const int idx = n * 256 + (((c >> 3) ^ g) << 3) + (c & 7);
        const u16 h = f2bf(v[j]);
        sHi[idx] = h;
        if (wantlo) sLo[idx] = f2bf(v[j] - bf2f(h));
      }
    }
  }
  __syncthreads();

  if (z < 2) {
    // ---- Q or K: 3-term hi/lo GEMM ----
    u16x8 ahi[8], alo[8];
    {
      const int tr = w * 16 + l15;
      const int g = (tr & 7) ^ (tr >> 3);
#pragma unroll
      for (int kc = 0; kc < 8; ++kc) {
        const int ch = ((kc * 4 + quad) ^ g) << 3;
        ahi[kc] = *(const u16x8*)(sHi + tr * 256 + ch);
        alo[kc] = *(const u16x8*)(sLo + tr * 256 + ch);
      }
    }
    const u16* WH = WHi + (size_t)z * 65536;
    const u16* WL = WLo + (size_t)z * 65536;
    const float* bias = (z == 0) ? bq : bk;
    u16* OH = (z == 0) ? QHi : KHi;
    u16* OL = (z == 0) ? QLo : KLo;
#pragma unroll 1
    for (int cb = 0; cb < 16; ++cb) {
      f32x4 acc = {0.f, 0.f, 0.f, 0.f};
      const int co = cb * 16 + l15;
#pragma unroll
      for (int kc = 0; kc < 8; ++kc) {
        const u16x8 whi = *(const u16x8*)(WH + (size_t)co * 256 + kc * 32 + quad * 8);
        const u16x8 wlo = *(const u16x8*)(WL + (size_t)co * 256 + kc * 32 + quad * 8);
        acc = mfma16(ahi[kc], whi, acc);
        acc = mfma16(ahi[kc], wlo, acc);
        acc = mfma16(alo[kc], whi, acc);
      }
      const float bs = bias[co];
      const size_t base = ((size_t)b * Nn + q0 + w * 16 + quad * 4) * Cc + co;
#pragma unroll
      for (int r = 0; r < 4; ++r) {
        const float qv = acc[r] + bs;
        const u16 h = f2bf(qv);
        OH[base + (size_t)r * Cc] = h;
        OL[base + (size_t)r * Cc] = f2bf(qv - bf2f(h));
      }
    }
  } else {
    // ---- V^T: 1-term, c_out is M dim ----
#pragma unroll 1
    for (int mt = 0; mt < 4; ++mt) {
      const int co = w * 64 + mt * 16 + l15;
      u16x8 wf[8];
#pragma unroll
      for (int kc = 0; kc < 8; ++kc)
        wf[kc] = *(const u16x8*)(WHi + 131072 + (size_t)co * 256 + kc * 32 + quad * 8);
      const int corow = w * 64 + mt * 16 + quad * 4;
      float bs[4];
#pragma unroll
      for (int r = 0; r < 4; ++r) bs[r] = bv[corow + r];
#pragma unroll 1
      for (int nt = 0; nt < 4; ++nt) {
        f32x4 acc = {0.f, 0.f, 0.f, 0.f};
        const int tr = nt * 16 + l15;
        const int g = (tr & 7) ^ (tr >> 3);
#pragma unroll
        for (int kc = 0; kc < 8; ++kc) {
          const u16x8 yf = *(const u16x8*)(sHi + tr * 256 + (((kc * 4 + quad) ^ g) << 3));
          acc = mfma16(wf[kc], yf, acc);
        }
        u16* vout = Vw + ((size_t)b * Cc + corow) * Nn + q0 + nt * 16 + l15;
#pragma unroll
        for (int r = 0; r < 4; ++r)
          vout[(size_t)r * Nn] = f2bf(acc[r] + bs[r]);
      }
    }
  }
}

// ---------------------------------------------------------------------------
// Flash attention, K-split=2. grid (8, 36, 2) — blockIdx.x = batch (XCD/L2
// affinity). Block 256 = 4 waves x 16 queries. 32-key tiles, register-
// prefetch pipeline (prefetch kb+1 global->regs during compute of kb).
// Writes unnormalized O partials + (m, l) per row; merge_kernel combines.
// ---------------------------------------------------------------------------
__global__ __launch_bounds__(256, 2) void attn_kernel(
    const u16* __restrict__ QHi, const u16* __restrict__ QLo,
    const u16* __restrict__ KHi, const u16* __restrict__ KLo,
    const u16* __restrict__ Vw, float* __restrict__ Opart,
    float* __restrict__ Ml)
{
  __shared__ u16 sKhi[32 * 256];
  __shared__ u16 sKlo[32 * 256];
  __shared__ u16 sV[256 * 32];
  __shared__ u16 sP[4 * 512];
  const int t    = threadIdx.x;
  const int b    = blockIdx.x;
  const int q0   = blockIdx.y * 64;
  const int sp   = blockIdx.z;
  const int lane = t & 63;
  const int w    = t >> 6;
  const int quad = lane >> 4;
  const int l15  = lane & 15;

  // Q fragments (A-layout)
  u16x8 qhi[8], qlo[8];
  {
    const size_t qrow = ((size_t)b * Nn + q0 + w * 16 + l15) * Cc;
#pragma unroll
    for (int kc = 0; kc < 8; ++kc) {
      qhi[kc] = *(const u16x8*)(QHi + qrow + kc * 32 + quad * 8);
      qlo[kc] = *(const u16x8*)(QLo + qrow + kc * 32 + quad * 8);
    }
  }

  f32x4 o[16];
#pragma unroll
  for (int i = 0; i < 16; ++i) o[i] = (f32x4){0.f, 0.f, 0.f, 0.f};
  float mrow[4] = {-3e38f, -3e38f, -3e38f, -3e38f};
  float lrow[4] = {0.f, 0.f, 0.f, 0.f};

  const u16* KhiB = KHi + (size_t)b * Nn * Cc;
  const u16* KloB = KLo + (size_t)b * Nn * Cc;
  const u16* VB   = Vw + (size_t)b * Cc * Nn;
  const int gl = (l15 & 3) ^ ((l15 >> 2) & 3);

  // loop-invariant staging geometry
  const int krow = t >> 5;                         // 0..7
  const int kcol = t & 31;
  const int kswz = kcol ^ krow;                    // global 16B chunk for K
  const int vrow = t >> 2;                         // 0..63 (c = it*64+vrow)
  const int gv   = ((t >> 2) & 3) ^ ((t >> 4) & 3);
  const int vswz = (t & 3) ^ gv;                   // global 16B chunk for V

  u16x8 pk[4], pl[4], pv[4];
  // prefetch tile 0
  {
    const size_t kg0 = (size_t)sp * TPS * 32;
#pragma unroll
    for (int it = 0; it < 4; ++it) {
      const size_t kg = (kg0 + krow + it * 8) * Cc + kswz * 8;
      pk[it] = *(const u16x8*)(KhiB + kg);
      pl[it] = *(const u16x8*)(KloB + kg);
      pv[it] = *(const u16x8*)(VB + (size_t)(it * 64 + vrow) * Nn + kg0 + vswz * 8);
    }
  }

#pragma unroll 1
  for (int kb = 0; kb < TPS; ++kb) {
    __syncthreads();   // previous tile's LDS reads done
    // ---- store prefetched regs -> LDS ----
#pragma unroll
    for (int it = 0; it < 4; ++it) {
      *(u16x8*)(sKhi + (krow + it * 8) * 256 + kcol * 8) = pk[it];
      *(u16x8*)(sKlo + (krow + it * 8) * 256 + kcol * 8) = pl[it];
      *(u16x8*)(sV + (it * 64 + vrow) * 32 + (t & 3) * 8) = pv[it];
    }
    __syncthreads();
    // ---- prefetch next tile (no wait — drains at next store) ----
    if (kb + 1 < TPS) {
      const size_t kg0 = ((size_t)sp * TPS + kb + 1) * 32;
#pragma unroll
      for (int it = 0; it < 4; ++it) {
        const size_t kg = (kg0 + krow + it * 8) * Cc + kswz * 8;
        pk[it] = *(const u16x8*)(KhiB + kg);
        pl[it] = *(const u16x8*)(KloB + kg);
        pv[it] = *(const u16x8*)(VB + (size_t)(it * 64 + vrow) * Nn + kg0 + vswz * 8);
      }
    }

    // ---- S = Q K^T, 3-term hi/lo, two 16-key blocks ----
    f32x4 s0 = {0.f, 0.f, 0.f, 0.f}, s1 = {0.f, 0.f, 0.f, 0.f};
#pragma unroll
    for (int kc = 0; kc < 8; ++kc) {
      const int ch = ((kc * 4 + quad) ^ (l15 & 7)) * 8;
      const u16x8 kh0 = *(const u16x8*)(sKhi + l15 * 256 + ch);
      const u16x8 kl0 = *(const u16x8*)(sKlo + l15 * 256 + ch);
      const u16x8 kh1 = *(const u16x8*)(sKhi + (16 + l15) * 256 + ch);
      const u16x8 kl1 = *(const u16x8*)(sKlo + (16 + l15) * 256 + ch);
      s0 = mfma16(qhi[kc], kh0, s0);
      s1 = mfma16(qhi[kc], kh1, s1);
      s0 = mfma16(qhi[kc], kl0, s0);
      s1 = mfma16(qhi[kc], kl1, s1);
      s0 = mfma16(qlo[kc], kh0, s0);
      s1 = mfma16(qlo[kc], kh1, s1);
    }

    // ---- online softmax ----
    float al[4];
#pragma unroll
    for (int r = 0; r < 4; ++r) {
      float m0 = fmaxf(s0[r], s1[r]);
#pragma unroll
      for (int off = 1; off < 16; off <<= 1)
        m0 = fmaxf(m0, __shfl_xor(m0, off, 64));
      const float mn = fmaxf(mrow[r], m0);
      al[r] = exp2f((mrow[r] - mn) * L2E);
      mrow[r] = mn;
      const float p0 = exp2f((s0[r] - mn) * L2E);
      const float p1 = exp2f((s1[r] - mn) * L2E);
      s0[r] = p0; s1[r] = p1;
      float sum = p0 + p1;
#pragma unroll
      for (int off = 1; off < 16; off <<= 1)
        sum += __shfl_xor(sum, off, 64);
      lrow[r] = lrow[r] * al[r] + sum;
    }
#pragma unroll
    for (int i = 0; i < 16; ++i) {
#pragma unroll
      for (int r = 0; r < 4; ++r) o[i][r] *= al[r];
    }

    // ---- P: C/D -> LDS (wave-local) -> A layout ----
    {
      u16* P = sP + w * 512;
      const int kch0 = l15 >> 3;
#pragma unroll
      for (int r = 0; r < 4; ++r) {
        const int row = quad * 4 + r;
        const int gx = r ^ quad;
        P[row * 32 + ((kch0 ^ gx) << 3) + (l15 & 7)] = f2bf(s0[r]);
        P[row * 32 + (((2 + kch0) ^ gx) << 3) + (l15 & 7)] = f2bf(s1[r]);
      }
    }
    __builtin_amdgcn_s_waitcnt(0xC07F);  // lgkmcnt(0) only
    const u16x8 pf = *(const u16x8*)(sP + w * 512 + l15 * 32 + ((quad ^ gl) << 3));

    // ---- O += P V ----
#pragma unroll
    for (int cb2 = 0; cb2 < 16; ++cb2) {
      const int c = cb2 * 16 + l15;
      const u16x8 vf = *(const u16x8*)(sV + c * 32 + ((quad ^ gl) << 3));
      o[cb2] = mfma16(pf, vf, o[cb2]);
    }
  }

  // ---- epilogue: unnormalized partials ----
  float* Ob = Opart + ((size_t)sp * Bb + b) * (size_t)Cc * Nn;
#pragma unroll
  for (int cb2 = 0; cb2 < 16; ++cb2) {
    const int c = cb2 * 16 + l15;
    *(f32x4*)(Ob + (size_t)c * Nn + q0 + w * 16 + quad * 4) = o[cb2];
  }
  if (l15 == 0) {
    float* mlb = Ml + ((size_t)sp * Bb + b) * (size_t)Nn * 2;
#pragma unroll
    for (int r = 0; r < 4; ++r) {
      const int n = q0 + w * 16 + quad * 4 + r;
      mlb[n * 2]     = mrow[r];
      mlb[n * 2 + 1] = lrow[r];
    }
  }
}

// ---------------------------------------------------------------------------
// Merge the 2 K-split partials. One thread per (b, c, 4-token group).
// ---------------------------------------------------------------------------
__global__ void merge_kernel(const float* __restrict__ Opart,
                             const float* __restrict__ Ml,
                             float* __restrict__ out)
{
  const int idx = blockIdx.x * 256 + threadIdx.x;  // 8*256*576 total
  const int n4 = idx % 576;
  const int bc = idx / 576;
  const int b  = bc >> 8;
  const size_t o0off = (size_t)bc * Nn + n4 * 4;
  const f32x4 o0 = *(const f32x4*)(Opart + o0off);
  const f32x4 o1 = *(const f32x4*)(Opart + o0off + (size_t)Bb * Cc * Nn);
  const float* ml0 = Ml + (size_t)b * Nn * 2 + n4 * 8;
  const float* ml1 = ml0 + (size_t)Bb * Nn * 2;
  const f32x4 a0 = *(const f32x4*)ml0;
  const f32x4 a1 = *(const f32x4*)(ml0 + 4);
  const f32x4 c0 = *(const f32x4*)ml1;
  const f32x4 c1 = *(const f32x4*)(ml1 + 4);
  f32x4 r;
#pragma unroll
  for (int j = 0; j < 4; ++j) {
    const float m0 = (j < 2) ? a0[j * 2] : a1[(j - 2) * 2];
    const float l0 = (j < 2) ? a0[j * 2 + 1] : a1[(j - 2) * 2 + 1];
    const float m1 = (j < 2) ? c0[j * 2] : c1[(j - 2) * 2];
    const float l1 = (j < 2) ? c0[j * 2 + 1] : c1[(j - 2) * 2 + 1];
    const float m = fmaxf(m0, m1);
    const float w0 = exp2f((m0 - m) * L2E);
    const float w1 = exp2f((m1 - m) * L2E);
    r[j] = (o0[j] * w0 + o1[j] * w1) / (l0 * w0 + l1 * w1);
  }
  *(f32x4*)(out + o0off) = r;
}

extern "C" void kernel_launch(void* const* d_in, const int* in_sizes, int n_in,
                              void* d_out, int out_size, void* d_ws, size_t ws_size,
                              hipStream_t stream) {
  const float* x  = (const float*)d_in[0];
  const float* y  = (const float*)d_in[1];
  const float* Wq = (const float*)d_in[2];
  const float* bq = (const float*)d_in[3];
  const float* Wk = (const float*)d_in[4];
  const float* bk = (const float*)d_in[5];
  const float* Wv = (const float*)d_in[6];
  const float* bv = (const float*)d_in[7];
  float* out = (float*)d_out;

  const size_t NC = (size_t)Bb * Nn * Cc;   // 4,718,592
  u16* QHi = (u16*)d_ws;
  u16* QLo = QHi + NC;
  u16* KHi = QLo + NC;
  u16* KLo = KHi + NC;
  u16* Vw  = KLo + NC;
  u16* WHi = Vw + NC;
  u16* WLo = WHi + 3 * 65536;
  float* Opart = (float*)(WLo + 3 * 65536);          // 2*NC floats
  float* Ml    = Opart + (size_t)KSPLIT * NC;        // 2*8*2304*2 floats

  hipLaunchKernelGGL(prep_kernel, dim3(96), dim3(256), 0, stream,
                     Wq, Wk, Wv, WHi, WLo);
  hipLaunchKernelGGL(proj_kernel, dim3(Bb, QTILES, 3), dim3(256), 0, stream,
                     x, y, WHi, WLo, bq, bk, bv, QHi, QLo, KHi, KLo, Vw);
  hipLaunchKernelGGL(attn_kernel, dim3(Bb, QTILES, KSPLIT), dim3(256), 0, stream,
                     QHi, QLo, KHi, KLo, Vw, Opart, Ml);
  hipLaunchKernelGGL(merge_kernel, dim3(4608), dim3(256), 0, stream,
                     Opart, Ml, out);
}

// Round 4
// 420.460 us; speedup vs baseline: 1.4745x; 1.0264x over previous
//
#include <hip/hip_runtime.h>
#include <stdint.h>

#define Bb 8
#define Cc 256
#define Nn 2304
#define QTILES 36   // Nn / 64
#define KSPLIT 2
#define TPS 36      // 32-key tiles per split: 2304 / 32 / KSPLIT
#define L2E 1.44269504088896f

typedef unsigned short u16;
typedef __bf16 bf16;
typedef bf16 bf16x8 __attribute__((ext_vector_type(8)));
typedef u16  u16x8  __attribute__((ext_vector_type(8)));
typedef float f32x4 __attribute__((ext_vector_type(4)));

static __device__ __forceinline__ u16 f2bf(float f) {
  unsigned u = __builtin_bit_cast(unsigned, f);
  return (u16)((u + 0x7fffu + ((u >> 16) & 1u)) >> 16);
}
static __device__ __forceinline__ float bf2f(u16 h) {
  unsigned u = ((unsigned)h) << 16;
  return __builtin_bit_cast(float, u);
}
static __device__ __forceinline__ bf16x8 asbf(u16x8 v) {
  return __builtin_bit_cast(bf16x8, v);
}
static __device__ __forceinline__ f32x4 mfma16(u16x8 a, u16x8 b, f32x4 c) {
  return __builtin_amdgcn_mfma_f32_16x16x32_bf16(asbf(a), asbf(b), c, 0, 0, 0);
}

// async 16B global -> LDS (DMA, no VGPR roundtrip)
static __device__ __forceinline__ void gl2lds16(const u16* g, u16* l) {
  __builtin_amdgcn_global_load_lds(
      (const __attribute__((address_space(1))) unsigned int*)g,
      (__attribute__((address_space(3))) unsigned int*)l, 16, 0, 0);
}

// DPP row_ror reductions over 16 lanes (VALU pipe, not LDS/ds_swizzle)
template <int CTRL>
static __device__ __forceinline__ float dppmov(float x) {
  return __builtin_bit_cast(float,
      __builtin_amdgcn_mov_dpp(__builtin_bit_cast(int, x), CTRL, 0xF, 0xF, true));
}
static __device__ __forceinline__ float rowmax16(float x) {
  x = fmaxf(x, dppmov<0x121>(x));   // row_ror:1
  x = fmaxf(x, dppmov<0x122>(x));   // row_ror:2
  x = fmaxf(x, dppmov<0x124>(x));   // row_ror:4
  x = fmaxf(x, dppmov<0x128>(x));   // row_ror:8
  return x;
}
static __device__ __forceinline__ float rowsum16(float x) {
  x += dppmov<0x121>(x);
  x += dppmov<0x122>(x);
  x += dppmov<0x124>(x);
  x += dppmov<0x128>(x);
  return x;
}

// ---------------------------------------------------------------------------
// Prep: Wq,Wk,Wv fp32 [C][C] -> hi/lo bf16. WHi/WLo: [3][C*C] u16.
// ---------------------------------------------------------------------------
__global__ void prep_kernel(const float* __restrict__ Wq,
                            const float* __restrict__ Wk,
                            const float* __restrict__ Wv,
                            u16* __restrict__ WHi, u16* __restrict__ WLo)
{
  const int tid = blockIdx.x * 256 + threadIdx.x;   // 0..24575
  const int m   = tid >> 13;
  const int off = (tid & 8191) * 8;
  const float* src = (m == 0) ? Wq : (m == 1) ? Wk : Wv;
  const f32x4 a = *(const f32x4*)(src + off);
  const f32x4 c = *(const f32x4*)(src + off + 4);
  u16x8 hi, lo;
#pragma unroll
  for (int j = 0; j < 4; ++j) {
    u16 h = f2bf(a[j]); hi[j] = h; lo[j] = f2bf(a[j] - bf2f(h));
    u16 h2 = f2bf(c[j]); hi[j + 4] = h2; lo[j + 4] = f2bf(c[j] - bf2f(h2));
  }
  *(u16x8*)(WHi + (size_t)m * 65536 + off) = hi;
  *(u16x8*)(WLo + (size_t)m * 65536 + off) = lo;
}

// ---------------------------------------------------------------------------
// Projection v3 — ZERO LDS. Fragments built directly from global:
// stride-Nn scalar f32 loads are coalesced across the 16 l15-lanes (64B
// segments). z=0 Q (hi/lo out), z=1 K (hi/lo out), z=2 V^T (bf16 out).
// grid (8, 36, 3), block 256 = 4 waves.
// ---------------------------------------------------------------------------
__global__ __launch_bounds__(256, 3) void proj_kernel(
    const float* __restrict__ x, const float* __restrict__ y,
    const u16* __restrict__ WHi, const u16* __restrict__ WLo,
    const float* __restrict__ bq, const float* __restrict__ bk,
    const float* __restrict__ bv,
    u16* __restrict__ QHi, u16* __restrict__ QLo,
    u16* __restrict__ KHi, u16* __restrict__ KLo,
    u16* __restrict__ Vw)
{
  const int t    = threadIdx.x;
  const int b    = blockIdx.x;
  const int q0   = blockIdx.y * 64;
  const int z    = blockIdx.z;
  const int lane = t & 63;
  const int w    = t >> 6;
  const int quad = lane >> 4;
  const int l15  = lane & 15;

  if (z < 2) {
    // ---- A-frags: token = q0+w*16+l15, k = kc*32+quad*8+j, hi/lo split ----
    const float* src = (z == 0) ? x : y;
    const int tok = q0 + w * 16 + l15;
    u16x8 ahi[8], alo[8];
#pragma unroll
    for (int kc = 0; kc < 8; ++kc) {
      const float* p = src + ((size_t)b * Cc + kc * 32 + quad * 8) * Nn + tok;
      float av[8];
#pragma unroll
      for (int j = 0; j < 8; ++j) av[j] = p[(size_t)j * Nn];
#pragma unroll
      for (int j = 0; j < 8; ++j) {
        const u16 h = f2bf(av[j]);
        ahi[kc][j] = h;
        alo[kc][j] = f2bf(av[j] - bf2f(h));
      }
    }
    const u16* WH = WHi + (size_t)z * 65536;
    const u16* WL = WLo + (size_t)z * 65536;
    const float* bias = (z == 0) ? bq : bk;
    u16* OH = (z == 0) ? QHi : KHi;
    u16* OL = (z == 0) ? QLo : KLo;
#pragma unroll 1
    for (int cb = 0; cb < 16; ++cb) {
      f32x4 acc = {0.f, 0.f, 0.f, 0.f};
      const int co = cb * 16 + l15;
#pragma unroll
      for (int kc = 0; kc < 8; ++kc) {
        const u16x8 whi = *(const u16x8*)(WH + (size_t)co * 256 + kc * 32 + quad * 8);
        const u16x8 wlo = *(const u16x8*)(WL + (size_t)co * 256 + kc * 32 + quad * 8);
        acc = mfma16(ahi[kc], whi, acc);
        acc = mfma16(ahi[kc], wlo, acc);
        acc = mfma16(alo[kc], whi, acc);
      }
      const float bs = bias[co];
      const size_t base = ((size_t)b * Nn + q0 + w * 16 + quad * 4) * Cc + co;
#pragma unroll
      for (int r = 0; r < 4; ++r) {
        const float qv = acc[r] + bs;
        const u16 h = f2bf(qv);
        OH[base + (size_t)r * Cc] = h;
        OL[base + (size_t)r * Cc] = f2bf(qv - bf2f(h));
      }
    }
  } else {
    // ---- V^T: M = c_out; wave w covers c_out [w*64, w*64+64) ----
#pragma unroll 1
    for (int nt = 0; nt < 4; ++nt) {
      u16x8 yf[8];
      const int tok = q0 + nt * 16 + l15;
#pragma unroll
      for (int kc = 0; kc < 8; ++kc) {
        const float* p = y + ((size_t)b * Cc + kc * 32 + quad * 8) * Nn + tok;
        u16x8 f;
#pragma unroll
        for (int j = 0; j < 8; ++j) f[j] = f2bf(p[(size_t)j * Nn]);
        yf[kc] = f;
      }
#pragma unroll 1
      for (int mt = 0; mt < 4; ++mt) {
        const int co = w * 64 + mt * 16 + l15;   // A-frag row
        f32x4 acc = {0.f, 0.f, 0.f, 0.f};
#pragma unroll
        for (int kc = 0; kc < 8; ++kc) {
          const u16x8 wf = *(const u16x8*)(WHi + 131072 + (size_t)co * 256 + kc * 32 + quad * 8);
          acc = mfma16(wf, yf[kc], acc);
        }
        const int crow = w * 64 + mt * 16 + quad * 4;
        u16* vout = Vw + ((size_t)b * Cc + crow) * Nn + q0 + nt * 16 + l15;
#pragma unroll
        for (int r = 0; r < 4; ++r)
          vout[(size_t)r * Nn] = f2bf(acc[r] + bv[crow + r]);
      }
    }
  }
}

// ---------------------------------------------------------------------------
// Flash attention, K-split=2. grid (8, 36, 2), block 256 = 4 waves x 16 q.
// 32-key tiles staged via global_load_lds (16B DMA, conflict-free linear
// LDS layout; swizzle carried on the global address). 3-term hi/lo QK^T,
// bf16 PV. DPP row reductions. __launch_bounds__(256,3) -> 3 blocks/CU so
// the 72-blocks-per-XCD grid fits in one residency round (no tail).
// ---------------------------------------------------------------------------
__global__ __launch_bounds__(256, 3) void attn_kernel(
    const u16* __restrict__ QHi, const u16* __restrict__ QLo,
    const u16* __restrict__ KHi, const u16* __restrict__ KLo,
    const u16* __restrict__ Vw, float* __restrict__ Opart,
    float* __restrict__ Ml)
{
  __shared__ u16 sKhi[32 * 256];
  __shared__ u16 sKlo[32 * 256];
  __shared__ u16 sV[256 * 32];
  __shared__ u16 sP[4 * 512];
  const int t    = threadIdx.x;
  const int b    = blockIdx.x;
  const int q0   = blockIdx.y * 64;
  const int sp   = blockIdx.z;
  const int lane = t & 63;
  const int w    = t >> 6;
  const int quad = lane >> 4;
  const int l15  = lane & 15;

  // Q fragments (A-layout)
  u16x8 qhi[8], qlo[8];
  {
    const size_t qrow = ((size_t)b * Nn + q0 + w * 16 + l15) * Cc;
#pragma unroll
    for (int kc = 0; kc < 8; ++kc) {
      qhi[kc] = *(const u16x8*)(QHi + qrow + kc * 32 + quad * 8);
      qlo[kc] = *(const u16x8*)(QLo + qrow + kc * 32 + quad * 8);
    }
  }

  f32x4 o[16];
#pragma unroll
  for (int i = 0; i < 16; ++i) o[i] = (f32x4){0.f, 0.f, 0.f, 0.f};
  float mrow[4] = {-3e38f, -3e38f, -3e38f, -3e38f};
  float lrow[4] = {0.f, 0.f, 0.f, 0.f};

  const u16* KhiB = KHi + (size_t)b * Nn * Cc;
  const u16* KloB = KLo + (size_t)b * Nn * Cc;
  const u16* VB   = Vw + (size_t)b * Cc * Nn;
  const int gl = (l15 & 3) ^ ((l15 >> 2) & 3);

  // staging geometry: LDS side is linear t*16B (DMA-compatible);
  // the XOR swizzle is applied to the GLOBAL chunk index.
  const int krow = t >> 5;                 // 0..7
  const int kswz = (t & 31) ^ krow;        // global 16B chunk for K
  const int vrow = t >> 2;                 // 0..63
  const int gv   = (vrow & 3) ^ ((t >> 4) & 3);
  const int vswz = (t & 3) ^ gv;           // global 16B chunk for V

#pragma unroll 1
  for (int kb = 0; kb < TPS; ++kb) {
    __syncthreads();   // prev tile reads done (compiler drains counters)
    // ---- stage K hi/lo [32][256] + V^T [256][32] via LDS-DMA ----
    {
      const size_t kg0 = ((size_t)sp * TPS + kb) * 32;
#pragma unroll
      for (int it = 0; it < 4; ++it) {
        const size_t kg = (kg0 + krow + it * 8) * Cc + kswz * 8;
        gl2lds16(KhiB + kg, sKhi + it * 2048 + t * 8);
        gl2lds16(KloB + kg, sKlo + it * 2048 + t * 8);
        gl2lds16(VB + (size_t)(it * 64 + vrow) * Nn + kg0 + vswz * 8,
                 sV + it * 2048 + t * 8);
      }
    }
    __syncthreads();   // compiler emits s_waitcnt vmcnt(0) before barrier

    // ---- S = Q K^T, 3-term hi/lo, two 16-key blocks ----
    f32x4 s0 = {0.f, 0.f, 0.f, 0.f}, s1 = {0.f, 0.f, 0.f, 0.f};
#pragma unroll
    for (int kc = 0; kc < 8; ++kc) {
      const int ch = ((kc * 4 + quad) ^ (l15 & 7)) * 8;
      const u16x8 kh0 = *(const u16x8*)(sKhi + l15 * 256 + ch);
      const u16x8 kl0 = *(const u16x8*)(sKlo + l15 * 256 + ch);
      const u16x8 kh1 = *(const u16x8*)(sKhi + (16 + l15) * 256 + ch);
      const u16x8 kl1 = *(const u16x8*)(sKlo + (16 + l15) * 256 + ch);
      s0 = mfma16(qhi[kc], kh0, s0);
      s1 = mfma16(qhi[kc], kh1, s1);
      s0 = mfma16(qhi[kc], kl0, s0);
      s1 = mfma16(qhi[kc], kl1, s1);
      s0 = mfma16(qlo[kc], kh0, s0);
      s1 = mfma16(qlo[kc], kh1, s1);
    }

    // ---- online softmax (DPP row reductions over the 16 key-lanes) ----
    float al[4];
#pragma unroll
    for (int r = 0; r < 4; ++r) {
      const float m0 = rowmax16(fmaxf(s0[r], s1[r]));
      const float mn = fmaxf(mrow[r], m0);
      al[r] = exp2f((mrow[r] - mn) * L2E);
      mrow[r] = mn;
      const float p0 = exp2f((s0[r] - mn) * L2E);
      const float p1 = exp2f((s1[r] - mn) * L2E);
      s0[r] = p0; s1[r] = p1;
      lrow[r] = lrow[r] * al[r] + rowsum16(p0 + p1);
    }
    const bool need = (al[0] < 1.f) | (al[1] < 1.f) | (al[2] < 1.f) | (al[3] < 1.f);
    if (__any(need)) {
#pragma unroll
      for (int i = 0; i < 16; ++i) {
#pragma unroll
        for (int r = 0; r < 4; ++r) o[i][r] *= al[r];
      }
    }

    // ---- P: C/D -> LDS (wave-local) -> A layout ----
    {
      u16* P = sP + w * 512;
      const int kch0 = l15 >> 3;
#pragma unroll
      for (int r = 0; r < 4; ++r) {
        const int row = quad * 4 + r;
        const int gx = r ^ quad;
        P[row * 32 + ((kch0 ^ gx) << 3) + (l15 & 7)] = f2bf(s0[r]);
        P[row * 32 + (((2 + kch0) ^ gx) << 3) + (l15 & 7)] = f2bf(s1[r]);
      }
    }
    const u16x8 pf = *(const u16x8*)(sP + w * 512 + l15 * 32 + ((quad ^ gl) << 3));

    // ---- O += P V ----
#pragma unroll
    for (int cb2 = 0; cb2 < 16; ++cb2) {
      const int c = cb2 * 16 + l15;
      const u16x8 vf = *(const u16x8*)(sV + c * 32 + ((quad ^ gl) << 3));
      o[cb2] = mfma16(pf, vf, o[cb2]);
    }
  }

  // ---- epilogue: unnormalized partials ----
  float* Ob = Opart + ((size_t)sp * Bb + b) * (size_t)Cc * Nn;
#pragma unroll
  for (int cb2 = 0; cb2 < 16; ++cb2) {
    const int c = cb2 * 16 + l15;
    *(f32x4*)(Ob + (size_t)c * Nn + q0 + w * 16 + quad * 4) = o[cb2];
  }
  if (l15 == 0) {
    float* mlb = Ml + ((size_t)sp * Bb + b) * (size_t)Nn * 2;
#pragma unroll
    for (int r = 0; r < 4; ++r) {
      const int n = q0 + w * 16 + quad * 4 + r;
      mlb[n * 2]     = mrow[r];
      mlb[n * 2 + 1] = lrow[r];
    }
  }
}

// ---------------------------------------------------------------------------
// Merge the 2 K-split partials. One thread per (b, c, 4-token group).
// ---------------------------------------------------------------------------
__global__ void merge_kernel(const float* __restrict__ Opart,
                             const float* __restrict__ Ml,
                             float* __restrict__ out)
{
  const int idx = blockIdx.x * 256 + threadIdx.x;  // 8*256*576 total
  const int n4 = idx % 576;
  const int bc = idx / 576;
  const int b  = bc >> 8;
  const size_t o0off = (size_t)bc * Nn + n4 * 4;
  const f32x4 o0 = *(const f32x4*)(Opart + o0off);
  const f32x4 o1 = *(const f32x4*)(Opart + o0off + (size_t)Bb * Cc * Nn);
  const float* ml0 = Ml + (size_t)b * Nn * 2 + n4 * 8;
  const float* ml1 = ml0 + (size_t)Bb * Nn * 2;
  const f32x4 a0 = *(const f32x4*)ml0;
  const f32x4 a1 = *(const f32x4*)(ml0 + 4);
  const f32x4 c0 = *(const f32x4*)ml1;
  const f32x4 c1 = *(const f32x4*)(ml1 + 4);
  f32x4 r;
#pragma unroll
  for (int j = 0; j < 4; ++j) {
    const float m0 = (j < 2) ? a0[j * 2] : a1[(j - 2) * 2];
    const float l0 = (j < 2) ? a0[j * 2 + 1] : a1[(j - 2) * 2 + 1];
    const float m1 = (j < 2) ? c0[j * 2] : c1[(j - 2) * 2];
    const float l1 = (j < 2) ? c0[j * 2 + 1] : c1[(j - 2) * 2 + 1];
    const float m = fmaxf(m0, m1);
    const float w0 = exp2f((m0 - m) * L2E);
    const float w1 = exp2f((m1 - m) * L2E);
    r[j] = (o0[j] * w0 + o1[j] * w1) / (l0 * w0 + l1 * w1);
  }
  *(f32x4*)(out + o0off) = r;
}

extern "C" void kernel_launch(void* const* d_in, const int* in_sizes, int n_in,
                              void* d_out, int out_size, void* d_ws, size_t ws_size,
                              hipStream_t stream) {
  const float* x  = (const float*)d_in[0];
  const float* y  = (const float*)d_in[1];
  const float* Wq = (const float*)d_in[2];
  const float* bq = (const float*)d_in[3];
  const float* Wk = (const float*)d_in[4];
  const float* bk = (const float*)d_in[5];
  const float* Wv = (const float*)d_in[6];
  const float* bv = (const float*)d_in[7];
  float* out = (float*)d_out;

  const size_t NC = (size_t)Bb * Nn * Cc;   // 4,718,592
  u16* QHi = (u16*)d_ws;
  u16* QLo = QHi + NC;
  u16* KHi = QLo + NC;
  u16* KLo = KHi + NC;
  u16* Vw  = KLo + NC;
  u16* WHi = Vw + NC;
  u16* WLo = WHi + 3 * 65536;
  float* Opart = (float*)(WLo + 3 * 65536);          // KSPLIT*NC floats
  float* Ml    = Opart + (size_t)KSPLIT * NC;        // KSPLIT*8*2304*2 floats

  hipLaunchKernelGGL(prep_kernel, dim3(96), dim3(256), 0, stream,
                     Wq, Wk, Wv, WHi, WLo);
  hipLaunchKernelGGL(proj_kernel, dim3(Bb, QTILES, 3), dim3(256), 0, stream,
                     x, y, WHi, WLo, bq, bk, bv, QHi, QLo, KHi, KLo, Vw);
  hipLaunchKernelGGL(attn_kernel, dim3(Bb, QTILES, KSPLIT), dim3(256), 0, stream,
                     QHi, QLo, KHi, KLo, Vw, Opart, Ml);
  hipLaunchKernelGGL(merge_kernel, dim3(4608), dim3(256), 0, stream,
                     Opart, Ml, out);
}